// Round 2
// baseline (952.413 us; speedup 1.0000x reference)
//
#include <hip/hip_runtime.h>

// LatentDynamicsModel fused: in-proj + GRU cell + out-proj.
// I/O is fp32 (per reference); internal GEMM math is bf16 MFMA with fp32 accum
// (test threshold 9.94e-2 permits bf16 rounding).
// B=131072, HID=256, LATENT=64, ACTION=2. One block = 32 batch rows, 4 waves.
// Weights pre-converted fp32->bf16 once per launch into d_ws (~1MB, L2-resident).
// Activations converted inline. Activations round-trip LDS (stride 264 pad).

typedef unsigned short u16;
typedef unsigned int u32;
using bf16x8 = __attribute__((ext_vector_type(8))) short;  // 8 bf16 (4 VGPRs)
using f32x4  = __attribute__((ext_vector_type(4))) float;  // 4 fp32 acc

constexpr int B_TOT = 131072;
constexpr int BM    = 32;    // batch rows per block
constexpr int SX    = 264;   // LDS row stride (256 + 8 pad -> 2-way bank aliasing, free)

// d_ws layout (u16 elements)
constexpr int OFF_WIN = 0;        // W_in padded: 256 rows x 72 (src rows of 66, pad 0)
constexpr int OFF_WIH = 18432;    // 768 x 256
constexpr int OFF_WHH = 215040;   // 768 x 256
constexpr int OFF_WO1 = 411648;   // 256 x 256
constexpr int OFF_WO2 = 477184;   // 64 x 256
constexpr int WS_TOT  = 493568;

__device__ __forceinline__ u16 f2b(float f) {  // RNE float->bf16
    u32 u = __builtin_bit_cast(u32, f);
    return (u16)((u + 0x7FFFu + ((u >> 16) & 1u)) >> 16);
}
__device__ __forceinline__ float sigm(float x) {
    x = fminf(fmaxf(x, -30.f), 30.f);
    float e = __expf(x);
    return e * __builtin_amdgcn_rcpf(1.f + e);
}
__device__ __forceinline__ float tanh_(float x) {
    x = fminf(fmaxf(x, -15.f), 15.f);
    float e = __expf(2.f * x);
    return (e - 1.f) * __builtin_amdgcn_rcpf(e + 1.f);
}
// load 8 consecutive fp32 -> bf16x8 frag (two dwordx4 loads + 8 RNE cvts)
__device__ __forceinline__ bf16x8 ld8f_bf(const float* __restrict__ p) {
    float4 a = *reinterpret_cast<const float4*>(p);
    float4 b = *reinterpret_cast<const float4*>(p + 4);
    bf16x8 r;
    r[0] = (short)f2b(a.x); r[1] = (short)f2b(a.y);
    r[2] = (short)f2b(a.z); r[3] = (short)f2b(a.w);
    r[4] = (short)f2b(b.x); r[5] = (short)f2b(b.y);
    r[6] = (short)f2b(b.z); r[7] = (short)f2b(b.w);
    return r;
}
__device__ __forceinline__ float b2f(u16 u) {
    u32 x = (u32)u << 16;
    return __builtin_bit_cast(float, x);
}

#define MFMA(a, b, c) __builtin_amdgcn_mfma_f32_16x16x32_bf16((a), (b), (c), 0, 0, 0)

// ---------- prep: convert all weights fp32 -> bf16 into ws ----------
__global__ void ldm_prep(const float* __restrict__ W_in, const float* __restrict__ W_ih,
                         const float* __restrict__ W_hh, const float* __restrict__ W_o1,
                         const float* __restrict__ W_o2, u16* __restrict__ ws)
{
    int i = blockIdx.x * blockDim.x + threadIdx.x;
    if (i >= WS_TOT) return;
    if (i < OFF_WIH) {                       // W_in padded to stride 72
        int r = i / 72, c = i - r * 72;
        ws[i] = (c < 66) ? f2b(W_in[r * 66 + c]) : (u16)0;
    } else if (i < OFF_WHH) {
        ws[i] = f2b(W_ih[i - OFF_WIH]);
    } else if (i < OFF_WO1) {
        ws[i] = f2b(W_hh[i - OFF_WHH]);
    } else if (i < OFF_WO2) {
        ws[i] = f2b(W_o1[i - OFF_WO1]);
    } else {
        ws[i] = f2b(W_o2[i - OFF_WO2]);
    }
}

// ---------- main fused kernel ----------
__global__ __launch_bounds__(256, 3)
void ldm_fused(const float* __restrict__ z, const float* __restrict__ act,
               const float* __restrict__ hid,
               const float* __restrict__ W_in_f, const float* __restrict__ b_in,
               const float* __restrict__ b_ih, const float* __restrict__ b_hh,
               const float* __restrict__ b_o1, const float* __restrict__ b_o2,
               const u16* __restrict__ ws,
               float* __restrict__ zn_out, float* __restrict__ h_out)
{
    __shared__ u16 xbuf[BM * SX];   // x (bf16), later reused for y
    __shared__ u16 hnew[BM * SX];   // h_new (bf16)

    const int tid  = threadIdx.x;
    const int w    = tid >> 6;      // wave 0..3
    const int lane = tid & 63;
    const int l16  = lane & 15;
    const int quad = lane >> 4;
    const int row0 = blockIdx.x * BM;

    const u16* Wib = ws + OFF_WIN;   // padded stride 72
    const u16* Wih = ws + OFF_WIH;
    const u16* Whh = ws + OFF_WHH;
    const u16* Wo1 = ws + OFF_WO1;
    const u16* Wo2 = ws + OFF_WO2;

    // ================= Stage A: x = relu([z|action] @ W_in^T + b_in) =================
    // K=64 via MFMA over z; action's 2 columns added in the epilogue (VALU).
    {
        bf16x8 az[2][2];  // [m-tile][k-chunk]
        #pragma unroll
        for (int mt = 0; mt < 2; ++mt) {
            const float* zp = z + (size_t)(row0 + mt * 16 + l16) * 64 + quad * 8;
            az[mt][0] = ld8f_bf(zp);
            az[mt][1] = ld8f_bf(zp + 32);
        }
        #pragma unroll
        for (int ot = 0; ot < 4; ++ot) {
            const int orow = w * 64 + ot * 16 + l16;  // output col / W_in row
            bf16x8 bw[2];
            #pragma unroll
            for (int kc = 0; kc < 2; ++kc)
                bw[kc] = *reinterpret_cast<const bf16x8*>(Wib + orow * 72 + kc * 32 + quad * 8);
            f32x4 acc[2];
            acc[0] = {0.f, 0.f, 0.f, 0.f};
            acc[1] = {0.f, 0.f, 0.f, 0.f};
            #pragma unroll
            for (int kc = 0; kc < 2; ++kc) {
                acc[0] = MFMA(az[0][kc], bw[kc], acc[0]);
                acc[1] = MFMA(az[1][kc], bw[kc], acc[1]);
            }
            // epilogue: + action outer-product + bias, relu, -> LDS (bf16)
            const float w64v = W_in_f[orow * 66 + 64];
            const float w65v = W_in_f[orow * 66 + 65];
            const float bi   = b_in[orow];
            #pragma unroll
            for (int mt = 0; mt < 2; ++mt) {
                #pragma unroll
                for (int i = 0; i < 4; ++i) {
                    const int rl = mt * 16 + quad * 4 + i;          // local row (C/D layout)
                    const float2 av = reinterpret_cast<const float2*>(act)[row0 + rl];
                    float v = acc[mt][i] + av.x * w64v + av.y * w65v + bi;
                    xbuf[rl * SX + orow] = f2b(fmaxf(v, 0.f));
                }
            }
        }
    }
    __syncthreads();

    // ================= Stage B: GRU gates =================
    // r,z gates accumulate over both K-halves (x·W_ih + h·W_hh); n keeps i_n / h_n separate.
    #pragma unroll 1
    for (int hf = 0; hf < 2; ++hf) {
        const int ob = w * 64 + hf * 32;   // this iteration covers output cols [ob, ob+32)
        f32x4 aR[2][2], aZ[2][2], aNi[2][2], aNh[2][2];  // [o-tile][m-tile]
        #pragma unroll
        for (int ot = 0; ot < 2; ++ot)
            #pragma unroll
            for (int mt = 0; mt < 2; ++mt) {
                aR[ot][mt]  = {0.f, 0.f, 0.f, 0.f};
                aZ[ot][mt]  = {0.f, 0.f, 0.f, 0.f};
                aNi[ot][mt] = {0.f, 0.f, 0.f, 0.f};
                aNh[ot][mt] = {0.f, 0.f, 0.f, 0.f};
            }
        // phase X: K over x (A-frags from LDS, bf16)
        #pragma unroll
        for (int kc = 0; kc < 8; ++kc) {
            bf16x8 ax[2];
            #pragma unroll
            for (int mt = 0; mt < 2; ++mt)
                ax[mt] = *reinterpret_cast<const bf16x8*>(&xbuf[(mt * 16 + l16) * SX + kc * 32 + quad * 8]);
            #pragma unroll
            for (int ot = 0; ot < 2; ++ot) {
                const int r0 = ob + ot * 16 + l16;
                const int ko = kc * 32 + quad * 8;
                const bf16x8 br_ = *reinterpret_cast<const bf16x8*>(Wih + (size_t)r0 * 256 + ko);
                const bf16x8 bz_ = *reinterpret_cast<const bf16x8*>(Wih + (size_t)(r0 + 256) * 256 + ko);
                const bf16x8 bn_ = *reinterpret_cast<const bf16x8*>(Wih + (size_t)(r0 + 512) * 256 + ko);
                #pragma unroll
                for (int mt = 0; mt < 2; ++mt) {
                    aR[ot][mt]  = MFMA(ax[mt], br_, aR[ot][mt]);
                    aZ[ot][mt]  = MFMA(ax[mt], bz_, aZ[ot][mt]);
                    aNi[ot][mt] = MFMA(ax[mt], bn_, aNi[ot][mt]);
                }
            }
        }
        // phase H: K over h (A-frags from global fp32, converted inline)
        #pragma unroll
        for (int kc = 0; kc < 8; ++kc) {
            bf16x8 ah[2];
            #pragma unroll
            for (int mt = 0; mt < 2; ++mt)
                ah[mt] = ld8f_bf(hid + (size_t)(row0 + mt * 16 + l16) * 256 + kc * 32 + quad * 8);
            #pragma unroll
            for (int ot = 0; ot < 2; ++ot) {
                const int r0 = ob + ot * 16 + l16;
                const int ko = kc * 32 + quad * 8;
                const bf16x8 br_ = *reinterpret_cast<const bf16x8*>(Whh + (size_t)r0 * 256 + ko);
                const bf16x8 bz_ = *reinterpret_cast<const bf16x8*>(Whh + (size_t)(r0 + 256) * 256 + ko);
                const bf16x8 bn_ = *reinterpret_cast<const bf16x8*>(Whh + (size_t)(r0 + 512) * 256 + ko);
                #pragma unroll
                for (int mt = 0; mt < 2; ++mt) {
                    aR[ot][mt]  = MFMA(ah[mt], br_, aR[ot][mt]);
                    aZ[ot][mt]  = MFMA(ah[mt], bz_, aZ[ot][mt]);
                    aNh[ot][mt] = MFMA(ah[mt], bn_, aNh[ot][mt]);
                }
            }
        }
        // gate epilogue
        #pragma unroll
        for (int ot = 0; ot < 2; ++ot) {
            const int o = ob + ot * 16 + l16;
            const float br_b = b_ih[o]       + b_hh[o];
            const float bz_b = b_ih[o + 256] + b_hh[o + 256];
            const float bni  = b_ih[o + 512];
            const float bnh  = b_hh[o + 512];
            #pragma unroll
            for (int mt = 0; mt < 2; ++mt) {
                #pragma unroll
                for (int i = 0; i < 4; ++i) {
                    const int rl = mt * 16 + quad * 4 + i;
                    const float hv = hid[(size_t)(row0 + rl) * 256 + o];
                    const float r  = sigm(aR[ot][mt][i] + br_b);
                    const float zg = sigm(aZ[ot][mt][i] + bz_b);
                    const float n  = tanh_(aNi[ot][mt][i] + bni + r * (aNh[ot][mt][i] + bnh));
                    const float hn = n + zg * (hv - n);   // (1-zg)*n + zg*h
                    hnew[rl * SX + o] = f2b(hn);
                }
            }
        }
    }
    __syncthreads();

    // coalesced h_new -> global (bf16 LDS -> fp32 stores, 32B per lane)
    #pragma unroll
    for (int it = 0; it < 4; ++it) {
        const int idx = it * 2048 + tid * 8;
        const int r = idx >> 8, c = idx & 255;
        const bf16x8 v = *reinterpret_cast<const bf16x8*>(&hnew[r * SX + c]);
        float4 f0, f1;
        f0.x = b2f((u16)v[0]); f0.y = b2f((u16)v[1]); f0.z = b2f((u16)v[2]); f0.w = b2f((u16)v[3]);
        f1.x = b2f((u16)v[4]); f1.y = b2f((u16)v[5]); f1.z = b2f((u16)v[6]); f1.w = b2f((u16)v[7]);
        float* dst = h_out + (size_t)(row0 + r) * 256 + c;
        *reinterpret_cast<float4*>(dst)     = f0;
        *reinterpret_cast<float4*>(dst + 4) = f1;
    }

    // ================= Stage 4: y = relu(h_new @ W_o1^T + b_o1) -> xbuf =================
    {
        f32x4 aY[4][2];
        #pragma unroll
        for (int ot = 0; ot < 4; ++ot) {
            aY[ot][0] = {0.f, 0.f, 0.f, 0.f};
            aY[ot][1] = {0.f, 0.f, 0.f, 0.f};
        }
        #pragma unroll
        for (int kc = 0; kc < 8; ++kc) {
            bf16x8 ah2[2];
            #pragma unroll
            for (int mt = 0; mt < 2; ++mt)
                ah2[mt] = *reinterpret_cast<const bf16x8*>(&hnew[(mt * 16 + l16) * SX + kc * 32 + quad * 8]);
            #pragma unroll
            for (int ot = 0; ot < 4; ++ot) {
                const bf16x8 bo = *reinterpret_cast<const bf16x8*>(
                    Wo1 + (size_t)(w * 64 + ot * 16 + l16) * 256 + kc * 32 + quad * 8);
                aY[ot][0] = MFMA(ah2[0], bo, aY[ot][0]);
                aY[ot][1] = MFMA(ah2[1], bo, aY[ot][1]);
            }
        }
        #pragma unroll
        for (int ot = 0; ot < 4; ++ot) {
            const int o = w * 64 + ot * 16 + l16;
            const float bo1 = b_o1[o];
            #pragma unroll
            for (int mt = 0; mt < 2; ++mt)
                #pragma unroll
                for (int i = 0; i < 4; ++i) {
                    const int rl = mt * 16 + quad * 4 + i;
                    xbuf[rl * SX + o] = f2b(fmaxf(aY[ot][mt][i] + bo1, 0.f));
                }
        }
    }
    __syncthreads();

    // ================= Stage 5: z_next = y @ W_o2^T + b_o2 =================
    {
        f32x4 aO[2];
        aO[0] = {0.f, 0.f, 0.f, 0.f};
        aO[1] = {0.f, 0.f, 0.f, 0.f};
        #pragma unroll
        for (int kc = 0; kc < 8; ++kc) {
            bf16x8 ay[2];
            #pragma unroll
            for (int mt = 0; mt < 2; ++mt)
                ay[mt] = *reinterpret_cast<const bf16x8*>(&xbuf[(mt * 16 + l16) * SX + kc * 32 + quad * 8]);
            const bf16x8 bo2 = *reinterpret_cast<const bf16x8*>(
                Wo2 + (size_t)(w * 16 + l16) * 256 + kc * 32 + quad * 8);
            aO[0] = MFMA(ay[0], bo2, aO[0]);
            aO[1] = MFMA(ay[1], bo2, aO[1]);
        }
        const int o = w * 16 + l16;   // 4 waves x 16 = 64 output cols
        const float bz2 = b_o2[o];
        #pragma unroll
        for (int mt = 0; mt < 2; ++mt)
            #pragma unroll
            for (int i = 0; i < 4; ++i) {
                const int rl = mt * 16 + quad * 4 + i;
                zn_out[(size_t)(row0 + rl) * 64 + o] = aO[mt][i] + bz2;
            }
    }
}

extern "C" void kernel_launch(void* const* d_in, const int* in_sizes, int n_in,
                              void* d_out, int out_size, void* d_ws, size_t ws_size,
                              hipStream_t stream) {
    const float* z    = (const float*)d_in[0];
    const float* act  = (const float*)d_in[1];
    const float* hid  = (const float*)d_in[2];
    const float* W_in = (const float*)d_in[3];
    const float* b_in = (const float*)d_in[4];
    const float* W_ih = (const float*)d_in[5];
    const float* W_hh = (const float*)d_in[6];
    const float* b_ih = (const float*)d_in[7];
    const float* b_hh = (const float*)d_in[8];
    const float* W_o1 = (const float*)d_in[9];
    const float* b_o1 = (const float*)d_in[10];
    const float* W_o2 = (const float*)d_in[11];
    const float* b_o2 = (const float*)d_in[12];

    u16* ws = (u16*)d_ws;

    float* zn_out = (float*)d_out;                      // [B, 64]
    float* h_out  = zn_out + (size_t)B_TOT * 64;        // [1, B, 256]

    ldm_prep<<<dim3((WS_TOT + 255) / 256), dim3(256), 0, stream>>>(
        W_in, W_ih, W_hh, W_o1, W_o2, ws);

    ldm_fused<<<dim3(B_TOT / BM), dim3(256), 0, stream>>>(
        z, act, hid, W_in, b_in, b_ih, b_hh, b_o1, b_o2, ws, zn_out, h_out);
}